// Round 5
// baseline (43506.927 us; speedup 1.0000x reference)
//
#include <hip/hip_runtime.h>

// VQ-VAE vector quantizer, MI355X round 5.
// Distance GEMM via 6-chain bf16x3-split MFMA; exact-fp32-replication
// preserved by a 2Sum midpoint-risk flag + round-4-bit-identical fp32 rescan
// of flagged rows. Unflagged rows provably match round 4 (which passed, abs 0).
// z: [2,512,8,32,32] fp32 ; emb: [8192,512] fp32
// out: z_q_ste (8388608 f32) | vq_loss (1 f32) | indices (16384 f32)

constexpr int KCB = 8192;
constexpr int CD  = 512;
constexpr int SD  = 8192;
constexpr int NB  = 2;
constexpr int NR  = NB * SD;                    // 16384
constexpr long ZQ_ELEMS = (long)NB * CD * SD;   // 8388608

// ws layout (non-overlapping):
//   0        : double mse acc (8B)
//   64       : uint rescan cnt
//   128      : u64 keys[16384]       -> 131200
//   139264   : u32 riskArr[16384]    -> 204800
//   212992   : int idxArr[16384]     -> 278528
//   286720   : int list[16384]       -> 352256
//   360448   : f32 znorm[16384]      -> 425984
//   425984   : f32 enorm[8192]       -> 458752
//   458752   : f32 embt[512*8192]    -> 17235968   (16MB, for rescan)
//   17235968 : bf16 eh[8192*512]     -> 25624576
//   25624576 : bf16 em[8192*512]     -> 34013184
//   34013184 : bf16 el[8192*512]     -> 42401792   (~40.4MB total)
constexpr size_t WS_CNT   = 64;
constexpr size_t WS_KEYS  = 128;
constexpr size_t WS_RISK  = 139264;
constexpr size_t WS_IDX   = 212992;
constexpr size_t WS_LIST  = 286720;
constexpr size_t WS_ZNORM = 360448;
constexpr size_t WS_ENORM = 425984;
constexpr size_t WS_EMBT  = 458752;
constexpr size_t WS_EH    = 17235968;
constexpr size_t WS_EM    = 25624576;
constexpr size_t WS_EL    = 34013184;

#define RISK_EPS 1.0e-7f     // >= 2.5x bound on |2*(dot_mfma - dot_fp32seq)|
#define WINDOW   1.3e-4f     // >= 2 grid steps at ulp(512..1024)=6.1e-5

typedef __attribute__((ext_vector_type(8))) short short8;
typedef __attribute__((ext_vector_type(4))) float f32x4;

__device__ __forceinline__ unsigned int fkey(float f) {
  unsigned int b = __float_as_uint(f);
  return (b & 0x80000000u) ? ~b : (b | 0x80000000u);
}
__device__ __forceinline__ ushort bf16_rne(float f, float* back) {
  unsigned int u = __float_as_uint(f);
  ushort h = (ushort)((u + 0x7FFFu + ((u >> 16) & 1u)) >> 16);
  *back = __uint_as_float((unsigned int)h << 16);
  return h;
}

// ---- znorm[n] = fp32(sum_c z[n][c]^2), fp64 accumulate (IDENTICAL to r4) ----
__global__ __launch_bounds__(256) void k_znorm(const float* __restrict__ z,
                                               float* __restrict__ znorm) {
  int n0 = blockIdx.x * 256;
  int b = n0 / SD, s0 = n0 % SD;
  const float* zp = z + (size_t)b * CD * SD + s0 + threadIdx.x;
  double a = 0.0;
  #pragma unroll 8
  for (int c = 0; c < CD; ++c) {
    double v = (double)zp[(size_t)c * SD];
    a = fma(v, v, a);
  }
  znorm[n0 + threadIdx.x] = (float)a;
}

// ---- enorm[k] (IDENTICAL to r4) ----
__global__ __launch_bounds__(256) void k_enorm(const float* __restrict__ emb,
                                               float* __restrict__ enorm) {
  int row  = blockIdx.x * 4 + (threadIdx.x >> 6);
  int lane = threadIdx.x & 63;
  const float4* p = (const float4*)(emb + (size_t)row * CD);
  float4 a = p[lane * 2], b = p[lane * 2 + 1];
  float s = a.x*a.x + a.y*a.y + a.z*a.z + a.w*a.w
          + b.x*b.x + b.y*b.y + b.z*b.z + b.w*b.w;
  #pragma unroll
  for (int off = 32; off; off >>= 1) s += __shfl_down(s, off);
  if (lane == 0) enorm[row] = s;
}

// ---- emb_t[c][k] = emb[k][c] (IDENTICAL to r4; feeds the rescan) ----
__global__ __launch_bounds__(256) void k_transpose(const float* __restrict__ emb,
                                                   float* __restrict__ embt) {
  __shared__ float t[64][65];
  int bk = blockIdx.x & 127, bc = blockIdx.x >> 7;
  int k0 = bk * 64, c0 = bc * 64;
  int t4 = threadIdx.x & 15, tq = threadIdx.x >> 4;
  #pragma unroll
  for (int p = 0; p < 4; ++p) {
    int kk = p * 16 + tq;
    float4 v = *(const float4*)(emb + (size_t)(k0 + kk) * CD + c0 + 4 * t4);
    t[kk][4*t4+0] = v.x; t[kk][4*t4+1] = v.y; t[kk][4*t4+2] = v.z; t[kk][4*t4+3] = v.w;
  }
  __syncthreads();
  #pragma unroll
  for (int p = 0; p < 4; ++p) {
    int cc = p * 16 + tq;
    float4 v;
    v.x = t[4*t4+0][cc]; v.y = t[4*t4+1][cc]; v.z = t[4*t4+2][cc]; v.w = t[4*t4+3][cc];
    *(float4*)(embt + (size_t)(c0 + cc) * KCB + k0 + 4 * t4) = v;
  }
}

// ---- emb -> 3 bf16 split planes (row-major [k][c]) ----
__global__ __launch_bounds__(256) void k_esplit(const float* __restrict__ emb,
                                                ushort* __restrict__ eh,
                                                ushort* __restrict__ em,
                                                ushort* __restrict__ el) {
  size_t base = (size_t)blockIdx.x * 2048 + (size_t)threadIdx.x * 8;
  float4 v0 = *(const float4*)(emb + base);
  float4 v1 = *(const float4*)(emb + base + 4);
  float vv[8] = {v0.x, v0.y, v0.z, v0.w, v1.x, v1.y, v1.z, v1.w};
  union { ushort u[8]; int4 v; } ph, pm, pl;
  #pragma unroll
  for (int i = 0; i < 8; ++i) {
    float fh, fm, fl2;
    ph.u[i] = bf16_rne(vv[i], &fh);
    float r1 = vv[i] - fh;
    pm.u[i] = bf16_rne(r1, &fm);
    float r2 = r1 - fm;
    pl.u[i] = bf16_rne(r2, &fl2);
  }
  *(int4*)(eh + base) = ph.v;
  *(int4*)(em + base) = pm.v;
  *(int4*)(el + base) = pl.v;
}

// ---- MFMA distance kernel ----
// 256 blocks x 512 thr (8 waves, 2Mx4N). Block: 128 rows x one khalf (4096),
// N-iters of 256 cols, K-steps of 32. 6-chain bf16x3 MFMA 16x16x32.
__global__ __launch_bounds__(512, 2) void k_dist_mfma(
    const float* __restrict__ z,
    const ushort* __restrict__ eh, const ushort* __restrict__ em,
    const ushort* __restrict__ el,
    const float* __restrict__ enorm, const float* __restrict__ znorm,
    unsigned long long* __restrict__ keys, unsigned int* __restrict__ riskArr) {
  extern __shared__ __align__(16) char smem[];
  ushort* Bh = (ushort*)(smem);              // [256][40]
  ushort* Bm = (ushort*)(smem + 20480);
  ushort* Bl = (ushort*)(smem + 40960);
  ushort* Ah = (ushort*)(smem + 61440);      // [128][40], k-block XOR swizzle
  ushort* Am = (ushort*)(smem + 71680);
  ushort* Al = (ushort*)(smem + 81920);      // total 92160 B

  int tid  = threadIdx.x;
  int lane = tid & 63, wid = tid >> 6;
  int wm = wid >> 2, wn = wid & 3;
  int lk = lane >> 4, lc = lane & 15;

  int m0    = (blockIdx.x >> 1) * 128;
  int kbase = (blockIdx.x & 1) * 4096;
  int bb = m0 >> 13, s0 = m0 & (SD - 1);
  const float* zb = z + (size_t)bb * CD * SD + s0;

  int sa_cr = tid >> 4;            // A-stage: c row 0..31
  int sa_nb = tid & 15;            // A-stage: 8-float n chunk
  int sb_row  = tid >> 1;          // B-stage: n row 0..255
  int sb_half = tid & 1;

  float Aab[16];
  #pragma unroll
  for (int li = 0; li < 16; ++li)
    Aab[li] = znorm[m0 + wm*64 + (li>>2)*16 + lk*4 + (li&3)];

  unsigned long long bkey[16];
  float bmin[16];
  #pragma unroll
  for (int li = 0; li < 16; ++li) { bkey[li] = ~0ull; bmin[li] = 3.4e38f; }
  unsigned int riskm = 0;

  for (int it = 0; it < 16; ++it) {
    int N0 = kbase + it * 256;
    f32x4 acc[4][4];
    #pragma unroll
    for (int mi = 0; mi < 4; ++mi)
      #pragma unroll
      for (int ni = 0; ni < 4; ++ni) {
        f32x4 zz = {0.f, 0.f, 0.f, 0.f};
        acc[mi][ni] = zz;
      }

    for (int ks = 0; ks < 16; ++ks) {
      int c0 = ks * 32;
      __syncthreads();
      // stage B (3 bf16 planes, coalesced)
      {
        size_t gsrc = (size_t)(N0 + sb_row) * CD + c0 + sb_half * 16;
        int dst = sb_row * 40 + sb_half * 16;
        *(int4*)(Bh + dst)     = *(const int4*)(eh + gsrc);
        *(int4*)(Bh + dst + 8) = *(const int4*)(eh + gsrc + 8);
        *(int4*)(Bm + dst)     = *(const int4*)(em + gsrc);
        *(int4*)(Bm + dst + 8) = *(const int4*)(em + gsrc + 8);
        *(int4*)(Bl + dst)     = *(const int4*)(el + gsrc);
        *(int4*)(Bl + dst + 8) = *(const int4*)(el + gsrc + 8);
      }
      // stage A: read z fp32 [c][n], split to bf16x3, swizzled scatter
      {
        const float* src = zb + (size_t)(c0 + sa_cr) * SD + sa_nb * 8;
        float4 v0 = *(const float4*)(src);
        float4 v1 = *(const float4*)(src + 4);
        float vv[8] = {v0.x, v0.y, v0.z, v0.w, v1.x, v1.y, v1.z, v1.w};
        int kb = sa_cr >> 3, kin = sa_cr & 7;
        #pragma unroll
        for (int i = 0; i < 8; ++i) {
          int n = sa_nb * 8 + i;
          int col = ((kb ^ ((n >> 3) & 3)) << 3) + kin;
          float fh, fm, fl2;
          ushort h = bf16_rne(vv[i], &fh);
          float r1 = vv[i] - fh;
          ushort m = bf16_rne(r1, &fm);
          float r2 = r1 - fm;
          ushort l = bf16_rne(r2, &fl2);
          Ah[n * 40 + col] = h;
          Am[n * 40 + col] = m;
          Al[n * 40 + col] = l;
        }
      }
      __syncthreads();
      // fragments + MFMA
      short8 a_h[4], a_m[4], a_l[4];
      #pragma unroll
      for (int mi = 0; mi < 4; ++mi) {
        int rowA = wm * 64 + mi * 16 + lc;
        int off = rowA * 40 + ((lk ^ ((rowA >> 3) & 3)) << 3);
        a_h[mi] = *(const short8*)(Ah + off);
        a_m[mi] = *(const short8*)(Am + off);
        a_l[mi] = *(const short8*)(Al + off);
      }
      #pragma unroll
      for (int ni = 0; ni < 4; ++ni) {
        int boff = (wn * 64 + ni * 16 + lc) * 40 + lk * 8;
        short8 b_h = *(const short8*)(Bh + boff);
        short8 b_m = *(const short8*)(Bm + boff);
        short8 b_l = *(const short8*)(Bl + boff);
        #pragma unroll
        for (int mi = 0; mi < 4; ++mi)
          acc[mi][ni] = __builtin_amdgcn_mfma_f32_16x16x32_bf16(a_h[mi], b_h, acc[mi][ni], 0, 0, 0);
        #pragma unroll
        for (int mi = 0; mi < 4; ++mi)
          acc[mi][ni] = __builtin_amdgcn_mfma_f32_16x16x32_bf16(a_h[mi], b_m, acc[mi][ni], 0, 0, 0);
        #pragma unroll
        for (int mi = 0; mi < 4; ++mi)
          acc[mi][ni] = __builtin_amdgcn_mfma_f32_16x16x32_bf16(a_m[mi], b_h, acc[mi][ni], 0, 0, 0);
        #pragma unroll
        for (int mi = 0; mi < 4; ++mi)
          acc[mi][ni] = __builtin_amdgcn_mfma_f32_16x16x32_bf16(a_h[mi], b_l, acc[mi][ni], 0, 0, 0);
        #pragma unroll
        for (int mi = 0; mi < 4; ++mi)
          acc[mi][ni] = __builtin_amdgcn_mfma_f32_16x16x32_bf16(a_m[mi], b_m, acc[mi][ni], 0, 0, 0);
        #pragma unroll
        for (int mi = 0; mi < 4; ++mi)
          acc[mi][ni] = __builtin_amdgcn_mfma_f32_16x16x32_bf16(a_l[mi], b_h, acc[mi][ni], 0, 0, 0);
      }
    }
    // epilogue: quantized d, key-min, 2Sum midpoint risk
    #pragma unroll
    for (int ni = 0; ni < 4; ++ni) {
      int col = N0 + wn * 64 + ni * 16 + lc;
      float en = enorm[col];
      #pragma unroll
      for (int mi = 0; mi < 4; ++mi) {
        #pragma unroll
        for (int r = 0; r < 4; ++r) {
          int li = mi * 4 + r;
          float ab = Aab[li] + en;            // identical to r4's ab
          float q  = -2.0f * acc[mi][ni][r];  // exact scaling
          float s  = ab + q;                  // = r4's d up to dot-delta
          float bvv = s - ab;                 // Fast2Sum (|ab| >> |q|): exact
          float t   = q - bvv;                // exact rounding residual
          unsigned int su = __float_as_uint(s);
          float ulp = __uint_as_float(su & 0x7f800000u) * 1.1920929e-7f;
          bool risky = (0.5f * ulp - fabsf(t)) < RISK_EPS;
          if (((su & 0x7fffffu) == 0u) && (t < 0.f))   // power-of-2 lower edge
            risky |= ((0.25f * ulp + t) < RISK_EPS);
          unsigned long long key =
              ((unsigned long long)fkey(s) << 32) | (unsigned int)col;
          if (key < bkey[li]) bkey[li] = key;
          if (s < bmin[li]) bmin[li] = s;
          if (risky && (s <= bmin[li] + WINDOW)) riskm |= (1u << li);
        }
      }
    }
  }
  // block reduction (reuse LDS)
  __syncthreads();
  unsigned long long* red = (unsigned long long*)smem;   // [128][64]
  #pragma unroll
  for (int li = 0; li < 16; ++li) {
    int row = wm * 64 + (li >> 2) * 16 + lk * 4 + (li & 3);
    red[row * 64 + wn * 16 + lc] = bkey[li];
  }
  __syncthreads();
  if (tid < 128) {
    unsigned long long mn = ~0ull;
    #pragma unroll 4
    for (int i = 0; i < 64; ++i) {
      unsigned long long v = red[tid * 64 + i];
      if (v < mn) mn = v;
    }
    atomicMin(&keys[m0 + tid], mn);
  }
  __syncthreads();
  unsigned int* red2 = (unsigned int*)smem;              // [128][64]
  #pragma unroll
  for (int li = 0; li < 16; ++li) {
    int row = wm * 64 + (li >> 2) * 16 + lk * 4 + (li & 3);
    red2[row * 64 + wn * 16 + lc] = (riskm >> li) & 1u;
  }
  __syncthreads();
  if (tid < 128) {
    unsigned int o = 0;
    #pragma unroll 4
    for (int i = 0; i < 64; ++i) o |= red2[tid * 64 + i];
    if (o) atomicOr(&riskArr[m0 + tid], 1u);
  }
}

// ---- resolve: idx from keys; flag risky rows into list ----
__global__ __launch_bounds__(256) void k_resolve(const unsigned long long* __restrict__ keys,
                                                 const unsigned int* __restrict__ riskArr,
                                                 int* __restrict__ idxArr,
                                                 int* __restrict__ list,
                                                 unsigned int* __restrict__ cnt) {
  int row = blockIdx.x * 256 + threadIdx.x;
  idxArr[row] = (int)(keys[row] & 0xffffffffull) & (KCB - 1);
  if (riskArr[row]) {
    unsigned int pos = atomicAdd(cnt, 1u);
    list[pos & (NR - 1)] = row;
  }
}

// ---- rescan: bit-identical round-4 fp32 path for flagged rows ----
__global__ __launch_bounds__(256) void k_rescan(const float* __restrict__ z,
                                                const float* __restrict__ embt,
                                                const float* __restrict__ enorm,
                                                const float* __restrict__ znorm,
                                                const int* __restrict__ list,
                                                const unsigned int* __restrict__ cnt,
                                                int* __restrict__ idxArr) {
  __shared__ float zs[512];
  __shared__ unsigned long long rk[256];
  int tid = threadIdx.x;
  unsigned int nr = *cnt;
  if (nr > (unsigned int)NR) nr = NR;
  for (unsigned int li = blockIdx.x; li < nr; li += gridDim.x) {
    int row = list[li] & (NR - 1);
    int b = row >> 13, s = row & (SD - 1);
    const float* zp = z + (size_t)b * CD * SD + s;
    zs[tid]       = zp[(size_t)tid * SD];
    zs[tid + 256] = zp[(size_t)(tid + 256) * SD];
    __syncthreads();
    float A = znorm[row];
    unsigned long long best = ~0ull;
    for (int k = tid; k < KCB; k += 256) {
      float acc = 0.f;
      #pragma unroll 8
      for (int c = 0; c < CD; ++c)            // ascending c: r4's exact order
        acc = fmaf(zs[c], embt[(size_t)c * KCB + k], acc);
      float ab = A + enorm[k];
      float d  = ab - 2.0f * acc;             // identical to r4 epilogue
      unsigned long long key =
          ((unsigned long long)fkey(d) << 32) | (unsigned int)k;
      if (key < best) best = key;
    }
    rk[tid] = best;
    __syncthreads();
    for (int s2 = 128; s2; s2 >>= 1) {
      if (tid < s2 && rk[tid + s2] < rk[tid]) rk[tid] = rk[tid + s2];
      __syncthreads();
    }
    if (tid == 0) idxArr[row] = (int)(rk[0] & 0xffffffffull) & (KCB - 1);
    __syncthreads();
  }
}

// ---- gather + STE + mse partial ----
__global__ __launch_bounds__(256) void k_gather(const float* __restrict__ z,
                                                const float* __restrict__ emb,
                                                const int* __restrict__ idxArr,
                                                float* __restrict__ out,
                                                double* __restrict__ acc) {
  __shared__ float q[16][516];
  __shared__ int   idxs[16];
  __shared__ float wpart[4];
  int tid = threadIdx.x;
  int n0 = blockIdx.x * 16;
  int b = n0 / SD, s0 = n0 % SD;
  if (tid < 16) {
    int idx = idxArr[n0 + tid] & (KCB - 1);
    idxs[tid] = idx;
    out[ZQ_ELEMS + 1 + n0 + tid] = (float)idx;
  }
  __syncthreads();
  int row = tid >> 4, c4 = (tid & 15) * 4;
  const float* esrc = emb + (size_t)idxs[row] * CD;
  #pragma unroll
  for (int p = 0; p < 8; ++p) {
    int c = c4 + p * 64;
    *(float4*)&q[row][c] = *(const float4*)(esrc + c);
  }
  __syncthreads();
  int si = tid & 15, cq = tid >> 4;
  float sum = 0.f;
  const float* zrd = z   + (size_t)b * CD * SD + s0 + si;
  float*       owr = out + (size_t)b * CD * SD + s0 + si;
  #pragma unroll
  for (int j = 0; j < 32; ++j) {
    int c = cq + 16 * j;
    float zv = zrd[(size_t)c * SD];
    float qv = q[si][c];
    float d = qv - zv;
    sum += d * d;
    owr[(size_t)c * SD] = zv + (qv - zv);
  }
  #pragma unroll
  for (int off = 32; off; off >>= 1) sum += __shfl_down(sum, off);
  if ((tid & 63) == 0) wpart[tid >> 6] = sum;
  __syncthreads();
  if (tid == 0) {
    double t = (double)wpart[0] + (double)wpart[1] + (double)wpart[2] + (double)wpart[3];
    atomicAdd(acc, t);
  }
}

__global__ void k_loss(const double* __restrict__ acc, float* __restrict__ out) {
  out[ZQ_ELEMS] = (float)(1.25 * (*acc) / (double)ZQ_ELEMS);
}

extern "C" void kernel_launch(void* const* d_in, const int* in_sizes, int n_in,
                              void* d_out, int out_size, void* d_ws, size_t ws_size,
                              hipStream_t stream) {
  const float* z   = (const float*)d_in[0];
  const float* emb = (const float*)d_in[1];
  float* out = (float*)d_out;
  double*             acc   = (double*)d_ws;
  unsigned int*       cnt   = (unsigned int*)((char*)d_ws + WS_CNT);
  unsigned long long* keys  = (unsigned long long*)((char*)d_ws + WS_KEYS);
  unsigned int*       risk  = (unsigned int*)((char*)d_ws + WS_RISK);
  int*                idxA  = (int*)((char*)d_ws + WS_IDX);
  int*                list  = (int*)((char*)d_ws + WS_LIST);
  float*              znorm = (float*)((char*)d_ws + WS_ZNORM);
  float*              enorm = (float*)((char*)d_ws + WS_ENORM);
  float*              embt  = (float*)((char*)d_ws + WS_EMBT);
  ushort*             eh    = (ushort*)((char*)d_ws + WS_EH);
  ushort*             em    = (ushort*)((char*)d_ws + WS_EM);
  ushort*             el    = (ushort*)((char*)d_ws + WS_EL);
  (void)in_sizes; (void)n_in; (void)out_size; (void)ws_size;

  hipMemsetAsync(d_ws, 0, 128, stream);                                  // acc+cnt
  hipMemsetAsync((char*)d_ws + WS_KEYS, 0xFF, (size_t)NR * 8, stream);   // keys
  hipMemsetAsync((char*)d_ws + WS_RISK, 0x00, (size_t)NR * 4, stream);   // risk

  k_znorm    <<<NR / 256, 256, 0, stream>>>(z, znorm);
  k_enorm    <<<KCB / 4, 256, 0, stream>>>(emb, enorm);
  k_transpose<<<(KCB / 64) * (CD / 64), 256, 0, stream>>>(emb, embt);
  k_esplit   <<<(KCB * CD) / 2048, 256, 0, stream>>>(emb, eh, em, el);
  k_dist_mfma<<<256, 512, 92160, stream>>>(z, eh, em, el, enorm, znorm, keys, risk);
  k_resolve  <<<NR / 256, 256, 0, stream>>>(keys, risk, idxA, list, cnt);
  k_rescan   <<<256, 256, 0, stream>>>(z, embt, enorm, znorm, list, cnt, idxA);
  k_gather   <<<NR / 16, 256, 0, stream>>>(z, emb, idxA, out, acc);
  k_loss     <<<1, 1, 0, stream>>>(acc, out);
}

// Round 6
// 1352.420 us; speedup vs baseline: 32.1697x; 32.1697x over previous
//
#include <hip/hip_runtime.h>

// VQ-VAE vector quantizer, MI355X round 6.
// bf16x3 6-chain MFMA distance GEMM; exact fp32-replication preserved by
// 2Sum midpoint-risk tracking (min-s over risky candidates, window test vs
// FINAL row min) + round-4-bit-identical fp32 rescan of flagged rows.
// z: [2,512,8,32,32] fp32 ; emb: [8192,512] fp32
// out: z_q_ste (8388608 f32) | vq_loss (1 f32) | indices (16384 f32)

constexpr int KCB = 8192;
constexpr int CD  = 512;
constexpr int SD  = 8192;
constexpr int NB  = 2;
constexpr int NR  = NB * SD;                    // 16384
constexpr long ZQ_ELEMS = (long)NB * CD * SD;   // 8388608

constexpr size_t WS_CNT   = 64;
constexpr size_t WS_KEYS  = 128;       // u64 keys[16384]      -> 131200
constexpr size_t WS_RISK  = 139264;    // u32 rminKey[16384]   -> 204800
constexpr size_t WS_IDX   = 212992;    // int idxArr[16384]    -> 278528
constexpr size_t WS_LIST  = 286720;    // int list[16384]      -> 352256
constexpr size_t WS_ZNORM = 360448;    // f32 znorm[16384]     -> 425984
constexpr size_t WS_ENORM = 425984;    // f32 enorm[8192]      -> 458752
constexpr size_t WS_EMBT  = 458752;    // f32 embt[512*8192]   -> 17235968
constexpr size_t WS_EH    = 17235968;  // bf16 planes
constexpr size_t WS_EM    = 25624576;
constexpr size_t WS_EL    = 34013184;  // -> 42401792

#define RISK_EPS 2.0e-7f   // >6-sigma bound on |2*(dot_mfma - dot_fp32seq)|
#define WINDOW   1.3e-4f   // >= 2 grid steps at ulp(512..1024)=6.1e-5

typedef __attribute__((ext_vector_type(8))) short short8;
typedef __attribute__((ext_vector_type(4))) float f32x4;

__device__ __forceinline__ unsigned int fkey(float f) {
  unsigned int b = __float_as_uint(f);
  return (b & 0x80000000u) ? ~b : (b | 0x80000000u);
}
__device__ __forceinline__ float unfkey(unsigned int u) {
  return (u & 0x80000000u) ? __uint_as_float(u ^ 0x80000000u)
                           : __uint_as_float(~u);
}
__device__ __forceinline__ ushort bf16_rne(float f, float* back) {
  unsigned int u = __float_as_uint(f);
  ushort h = (ushort)((u + 0x7FFFu + ((u >> 16) & 1u)) >> 16);
  *back = __uint_as_float((unsigned int)h << 16);
  return h;
}

// ---- znorm[n] = fp32(sum_c z[n][c]^2), fp64 accumulate ----
__global__ __launch_bounds__(256) void k_znorm(const float* __restrict__ z,
                                               float* __restrict__ znorm) {
  int n0 = blockIdx.x * 256;
  int b = n0 / SD, s0 = n0 % SD;
  const float* zp = z + (size_t)b * CD * SD + s0 + threadIdx.x;
  double a = 0.0;
  #pragma unroll 8
  for (int c = 0; c < CD; ++c) {
    double v = (double)zp[(size_t)c * SD];
    a = fma(v, v, a);
  }
  znorm[n0 + threadIdx.x] = (float)a;
}

// ---- enorm[k] ----
__global__ __launch_bounds__(256) void k_enorm(const float* __restrict__ emb,
                                               float* __restrict__ enorm) {
  int row  = blockIdx.x * 4 + (threadIdx.x >> 6);
  int lane = threadIdx.x & 63;
  const float4* p = (const float4*)(emb + (size_t)row * CD);
  float4 a = p[lane * 2], b = p[lane * 2 + 1];
  float s = a.x*a.x + a.y*a.y + a.z*a.z + a.w*a.w
          + b.x*b.x + b.y*b.y + b.z*b.z + b.w*b.w;
  #pragma unroll
  for (int off = 32; off; off >>= 1) s += __shfl_down(s, off);
  if (lane == 0) enorm[row] = s;
}

// ---- emb_t[c][k] = emb[k][c] (feeds the r4-identical rescan) ----
__global__ __launch_bounds__(256) void k_transpose(const float* __restrict__ emb,
                                                   float* __restrict__ embt) {
  __shared__ float t[64][65];
  int bk = blockIdx.x & 127, bc = blockIdx.x >> 7;
  int k0 = bk * 64, c0 = bc * 64;
  int t4 = threadIdx.x & 15, tq = threadIdx.x >> 4;
  #pragma unroll
  for (int p = 0; p < 4; ++p) {
    int kk = p * 16 + tq;
    float4 v = *(const float4*)(emb + (size_t)(k0 + kk) * CD + c0 + 4 * t4);
    t[kk][4*t4+0] = v.x; t[kk][4*t4+1] = v.y; t[kk][4*t4+2] = v.z; t[kk][4*t4+3] = v.w;
  }
  __syncthreads();
  #pragma unroll
  for (int p = 0; p < 4; ++p) {
    int cc = p * 16 + tq;
    float4 v;
    v.x = t[4*t4+0][cc]; v.y = t[4*t4+1][cc]; v.z = t[4*t4+2][cc]; v.w = t[4*t4+3][cc];
    *(float4*)(embt + (size_t)(c0 + cc) * KCB + k0 + 4 * t4) = v;
  }
}

// ---- emb -> 3 bf16 split planes ----
__global__ __launch_bounds__(256) void k_esplit(const float* __restrict__ emb,
                                                ushort* __restrict__ eh,
                                                ushort* __restrict__ em,
                                                ushort* __restrict__ el) {
  size_t base = (size_t)blockIdx.x * 2048 + (size_t)threadIdx.x * 8;
  float4 v0 = *(const float4*)(emb + base);
  float4 v1 = *(const float4*)(emb + base + 4);
  float vv[8] = {v0.x, v0.y, v0.z, v0.w, v1.x, v1.y, v1.z, v1.w};
  union { ushort u[8]; int4 v; } ph, pm, pl;
  #pragma unroll
  for (int i = 0; i < 8; ++i) {
    float fh, fm, fl2;
    ph.u[i] = bf16_rne(vv[i], &fh);
    float r1 = vv[i] - fh;
    pm.u[i] = bf16_rne(r1, &fm);
    float r2 = r1 - fm;
    pl.u[i] = bf16_rne(r2, &fl2);
  }
  *(int4*)(eh + base) = ph.v;
  *(int4*)(em + base) = pm.v;
  *(int4*)(el + base) = pl.v;
}

// ---- MFMA distance kernel (risk: min-s over risky, no running-min test) ----
__global__ __launch_bounds__(512, 2) void k_dist_mfma(
    const float* __restrict__ z,
    const ushort* __restrict__ eh, const ushort* __restrict__ em,
    const ushort* __restrict__ el,
    const float* __restrict__ enorm, const float* __restrict__ znorm,
    unsigned long long* __restrict__ keys, unsigned int* __restrict__ riskArr) {
  extern __shared__ __align__(16) char smem[];
  ushort* Bh = (ushort*)(smem);              // [256][40]
  ushort* Bm = (ushort*)(smem + 20480);
  ushort* Bl = (ushort*)(smem + 40960);
  ushort* Ah = (ushort*)(smem + 61440);      // [128][40], k-block XOR swizzle
  ushort* Am = (ushort*)(smem + 71680);
  ushort* Al = (ushort*)(smem + 81920);      // total 92160 B

  int tid  = threadIdx.x;
  int lane = tid & 63, wid = tid >> 6;
  int wm = wid >> 2, wn = wid & 3;
  int lk = lane >> 4, lc = lane & 15;

  int m0    = (blockIdx.x >> 1) * 128;
  int kbase = (blockIdx.x & 1) * 4096;
  int bb = m0 >> 13, s0 = m0 & (SD - 1);
  const float* zb = z + (size_t)bb * CD * SD + s0;

  int sa_cr = tid >> 4;
  int sa_nb = tid & 15;
  int sb_row  = tid >> 1;
  int sb_half = tid & 1;

  float Aab[16];
  #pragma unroll
  for (int li = 0; li < 16; ++li)
    Aab[li] = znorm[m0 + wm*64 + (li>>2)*16 + lk*4 + (li&3)];

  unsigned long long bkey[16];
  float rminv[16];
  #pragma unroll
  for (int li = 0; li < 16; ++li) { bkey[li] = ~0ull; rminv[li] = 3.402823466e38f; }

  for (int it = 0; it < 16; ++it) {
    int N0 = kbase + it * 256;
    f32x4 acc[4][4];
    #pragma unroll
    for (int mi = 0; mi < 4; ++mi)
      #pragma unroll
      for (int ni = 0; ni < 4; ++ni) {
        f32x4 zz = {0.f, 0.f, 0.f, 0.f};
        acc[mi][ni] = zz;
      }

    for (int ks = 0; ks < 16; ++ks) {
      int c0 = ks * 32;
      __syncthreads();
      {
        size_t gsrc = (size_t)(N0 + sb_row) * CD + c0 + sb_half * 16;
        int dst = sb_row * 40 + sb_half * 16;
        *(int4*)(Bh + dst)     = *(const int4*)(eh + gsrc);
        *(int4*)(Bh + dst + 8) = *(const int4*)(eh + gsrc + 8);
        *(int4*)(Bm + dst)     = *(const int4*)(em + gsrc);
        *(int4*)(Bm + dst + 8) = *(const int4*)(em + gsrc + 8);
        *(int4*)(Bl + dst)     = *(const int4*)(el + gsrc);
        *(int4*)(Bl + dst + 8) = *(const int4*)(el + gsrc + 8);
      }
      {
        const float* src = zb + (size_t)(c0 + sa_cr) * SD + sa_nb * 8;
        float4 v0 = *(const float4*)(src);
        float4 v1 = *(const float4*)(src + 4);
        float vv[8] = {v0.x, v0.y, v0.z, v0.w, v1.x, v1.y, v1.z, v1.w};
        int kb = sa_cr >> 3, kin = sa_cr & 7;
        #pragma unroll
        for (int i = 0; i < 8; ++i) {
          int n = sa_nb * 8 + i;
          int col = ((kb ^ ((n >> 3) & 3)) << 3) + kin;
          float fh, fm, fl2;
          ushort h = bf16_rne(vv[i], &fh);
          float r1 = vv[i] - fh;
          ushort m = bf16_rne(r1, &fm);
          float r2 = r1 - fm;
          ushort l = bf16_rne(r2, &fl2);
          Ah[n * 40 + col] = h;
          Am[n * 40 + col] = m;
          Al[n * 40 + col] = l;
        }
      }
      __syncthreads();
      short8 a_h[4], a_m[4], a_l[4];
      #pragma unroll
      for (int mi = 0; mi < 4; ++mi) {
        int rowA = wm * 64 + mi * 16 + lc;
        int off = rowA * 40 + ((lk ^ ((rowA >> 3) & 3)) << 3);
        a_h[mi] = *(const short8*)(Ah + off);
        a_m[mi] = *(const short8*)(Am + off);
        a_l[mi] = *(const short8*)(Al + off);
      }
      #pragma unroll
      for (int ni = 0; ni < 4; ++ni) {
        int boff = (wn * 64 + ni * 16 + lc) * 40 + lk * 8;
        short8 b_h = *(const short8*)(Bh + boff);
        short8 b_m = *(const short8*)(Bm + boff);
        short8 b_l = *(const short8*)(Bl + boff);
        #pragma unroll
        for (int mi = 0; mi < 4; ++mi)
          acc[mi][ni] = __builtin_amdgcn_mfma_f32_16x16x32_bf16(a_h[mi], b_h, acc[mi][ni], 0, 0, 0);
        #pragma unroll
        for (int mi = 0; mi < 4; ++mi)
          acc[mi][ni] = __builtin_amdgcn_mfma_f32_16x16x32_bf16(a_h[mi], b_m, acc[mi][ni], 0, 0, 0);
        #pragma unroll
        for (int mi = 0; mi < 4; ++mi)
          acc[mi][ni] = __builtin_amdgcn_mfma_f32_16x16x32_bf16(a_m[mi], b_h, acc[mi][ni], 0, 0, 0);
        #pragma unroll
        for (int mi = 0; mi < 4; ++mi)
          acc[mi][ni] = __builtin_amdgcn_mfma_f32_16x16x32_bf16(a_h[mi], b_l, acc[mi][ni], 0, 0, 0);
        #pragma unroll
        for (int mi = 0; mi < 4; ++mi)
          acc[mi][ni] = __builtin_amdgcn_mfma_f32_16x16x32_bf16(a_m[mi], b_m, acc[mi][ni], 0, 0, 0);
        #pragma unroll
        for (int mi = 0; mi < 4; ++mi)
          acc[mi][ni] = __builtin_amdgcn_mfma_f32_16x16x32_bf16(a_l[mi], b_h, acc[mi][ni], 0, 0, 0);
      }
    }
    // epilogue: quantized d, key-min, risky-min tracking
    #pragma unroll
    for (int ni = 0; ni < 4; ++ni) {
      int col = N0 + wn * 64 + ni * 16 + lc;
      float en = enorm[col];
      #pragma unroll
      for (int mi = 0; mi < 4; ++mi) {
        #pragma unroll
        for (int r = 0; r < 4; ++r) {
          int li = mi * 4 + r;
          float ab = Aab[li] + en;
          float q  = -2.0f * acc[mi][ni][r];
          float s  = ab + q;
          float bvv = s - ab;                 // Fast2Sum (|ab| >> |q|): exact
          float t   = q - bvv;                // exact rounding residual
          unsigned int su = __float_as_uint(s);
          float ulp = __uint_as_float(su & 0x7f800000u) * 1.1920929e-7f;
          bool risky = (0.5f * ulp - fabsf(t)) < RISK_EPS;
          if (((su & 0x7fffffu) == 0u) && (t < 0.f))   // pow2 lower edge
            risky |= ((0.25f * ulp + t) < RISK_EPS);
          unsigned long long key =
              ((unsigned long long)fkey(s) << 32) | (unsigned int)col;
          if (key < bkey[li]) bkey[li] = key;
          if (risky && s < rminv[li]) rminv[li] = s;
        }
      }
    }
  }
  // block reduction
  __syncthreads();
  unsigned long long* red = (unsigned long long*)smem;   // [128][64]
  #pragma unroll
  for (int li = 0; li < 16; ++li) {
    int row = wm * 64 + (li >> 2) * 16 + lk * 4 + (li & 3);
    red[row * 64 + wn * 16 + lc] = bkey[li];
  }
  __syncthreads();
  if (tid < 128) {
    unsigned long long mn = ~0ull;
    #pragma unroll 4
    for (int i = 0; i < 64; ++i) {
      unsigned long long v = red[tid * 64 + i];
      if (v < mn) mn = v;
    }
    atomicMin(&keys[m0 + tid], mn);
  }
  __syncthreads();
  unsigned int* red2 = (unsigned int*)smem;              // [128][64]
  #pragma unroll
  for (int li = 0; li < 16; ++li) {
    int row = wm * 64 + (li >> 2) * 16 + lk * 4 + (li & 3);
    red2[row * 64 + wn * 16 + lc] = fkey(rminv[li]);
  }
  __syncthreads();
  if (tid < 128) {
    unsigned int mn = 0xFFFFFFFFu;
    #pragma unroll 4
    for (int i = 0; i < 64; ++i) {
      unsigned int v = red2[tid * 64 + i];
      if (v < mn) mn = v;
    }
    atomicMin(&riskArr[m0 + tid], mn);
  }
}

// ---- resolve: window test vs FINAL global min ----
__global__ __launch_bounds__(256) void k_resolve(const unsigned long long* __restrict__ keys,
                                                 const unsigned int* __restrict__ riskArr,
                                                 int* __restrict__ idxArr,
                                                 int* __restrict__ list,
                                                 unsigned int* __restrict__ cnt) {
  int row = blockIdx.x * 256 + threadIdx.x;
  unsigned long long kk = keys[row];
  idxArr[row] = (int)(kk & 0xffffffffull) & (KCB - 1);
  float smin = unfkey((unsigned int)(kk >> 32));
  float rmin = unfkey(riskArr[row]);          // NaN when no risky candidate
  if (rmin <= smin + WINDOW) {
    unsigned int pos = atomicAdd(cnt, 1u);
    list[pos & (NR - 1)] = row;
  }
}

// ---- rescan: bit-identical r4 fp32 path, 4-way ILP ----
__global__ __launch_bounds__(256) void k_rescan(const float* __restrict__ z,
                                                const float* __restrict__ embt,
                                                const float* __restrict__ enorm,
                                                const float* __restrict__ znorm,
                                                const int* __restrict__ list,
                                                const unsigned int* __restrict__ cnt,
                                                int* __restrict__ idxArr) {
  __shared__ float zs[512];
  __shared__ unsigned long long rk[256];
  int tid = threadIdx.x;
  unsigned int nr = *cnt;
  if (nr > (unsigned int)NR) nr = NR;
  for (unsigned int li = blockIdx.x; li < nr; li += gridDim.x) {
    int row = list[li] & (NR - 1);
    int b = row >> 13, s = row & (SD - 1);
    const float* zp = z + (size_t)b * CD * SD + s;
    zs[tid]       = zp[(size_t)tid * SD];
    zs[tid + 256] = zp[(size_t)(tid + 256) * SD];
    __syncthreads();
    float A = znorm[row];
    unsigned long long best = ~0ull;
    #pragma unroll 1
    for (int g = 0; g < 8; ++g) {
      int ka = tid + g * 1024;                // 4 k's: ka + {0,256,512,768}
      float a0 = 0.f, a1 = 0.f, a2 = 0.f, a3 = 0.f;
      #pragma unroll 8
      for (int c = 0; c < CD; ++c) {          // ascending c: r4's exact order
        const float* ep = embt + (size_t)c * KCB + ka;
        float zc = zs[c];
        a0 = fmaf(zc, ep[0],   a0);
        a1 = fmaf(zc, ep[256], a1);
        a2 = fmaf(zc, ep[512], a2);
        a3 = fmaf(zc, ep[768], a3);
      }
      float av[4] = {a0, a1, a2, a3};
      #pragma unroll
      for (int jj = 0; jj < 4; ++jj) {
        int k = ka + jj * 256;
        float d = (A + enorm[k]) - 2.0f * av[jj];   // identical to r4
        unsigned long long key =
            ((unsigned long long)fkey(d) << 32) | (unsigned int)k;
        if (key < best) best = key;
      }
    }
    rk[tid] = best;
    __syncthreads();
    for (int s2 = 128; s2; s2 >>= 1) {
      if (tid < s2 && rk[tid + s2] < rk[tid]) rk[tid] = rk[tid + s2];
      __syncthreads();
    }
    if (tid == 0) idxArr[row] = (int)(rk[0] & 0xffffffffull) & (KCB - 1);
    __syncthreads();
  }
}

// ---- gather + STE + mse partial ----
__global__ __launch_bounds__(256) void k_gather(const float* __restrict__ z,
                                                const float* __restrict__ emb,
                                                const int* __restrict__ idxArr,
                                                float* __restrict__ out,
                                                double* __restrict__ acc) {
  __shared__ float q[16][516];
  __shared__ int   idxs[16];
  __shared__ float wpart[4];
  int tid = threadIdx.x;
  int n0 = blockIdx.x * 16;
  int b = n0 / SD, s0 = n0 % SD;
  if (tid < 16) {
    int idx = idxArr[n0 + tid] & (KCB - 1);
    idxs[tid] = idx;
    out[ZQ_ELEMS + 1 + n0 + tid] = (float)idx;
  }
  __syncthreads();
  int row = tid >> 4, c4 = (tid & 15) * 4;
  const float* esrc = emb + (size_t)idxs[row] * CD;
  #pragma unroll
  for (int p = 0; p < 8; ++p) {
    int c = c4 + p * 64;
    *(float4*)&q[row][c] = *(const float4*)(esrc + c);
  }
  __syncthreads();
  int si = tid & 15, cq = tid >> 4;
  float sum = 0.f;
  const float* zrd = z   + (size_t)b * CD * SD + s0 + si;
  float*       owr = out + (size_t)b * CD * SD + s0 + si;
  #pragma unroll
  for (int j = 0; j < 32; ++j) {
    int c = cq + 16 * j;
    float zv = zrd[(size_t)c * SD];
    float qv = q[si][c];
    float d = qv - zv;
    sum += d * d;
    owr[(size_t)c * SD] = zv + (qv - zv);
  }
  #pragma unroll
  for (int off = 32; off; off >>= 1) sum += __shfl_down(sum, off);
  if ((tid & 63) == 0) wpart[tid >> 6] = sum;
  __syncthreads();
  if (tid == 0) {
    double t = (double)wpart[0] + (double)wpart[1] + (double)wpart[2] + (double)wpart[3];
    atomicAdd(acc, t);
  }
}

__global__ void k_loss(const double* __restrict__ acc, float* __restrict__ out) {
  out[ZQ_ELEMS] = (float)(1.25 * (*acc) / (double)ZQ_ELEMS);
}

extern "C" void kernel_launch(void* const* d_in, const int* in_sizes, int n_in,
                              void* d_out, int out_size, void* d_ws, size_t ws_size,
                              hipStream_t stream) {
  const float* z   = (const float*)d_in[0];
  const float* emb = (const float*)d_in[1];
  float* out = (float*)d_out;
  double*             acc   = (double*)d_ws;
  unsigned int*       cnt   = (unsigned int*)((char*)d_ws + WS_CNT);
  unsigned long long* keys  = (unsigned long long*)((char*)d_ws + WS_KEYS);
  unsigned int*       risk  = (unsigned int*)((char*)d_ws + WS_RISK);
  int*                idxA  = (int*)((char*)d_ws + WS_IDX);
  int*                list  = (int*)((char*)d_ws + WS_LIST);
  float*              znorm = (float*)((char*)d_ws + WS_ZNORM);
  float*              enorm = (float*)((char*)d_ws + WS_ENORM);
  float*              embt  = (float*)((char*)d_ws + WS_EMBT);
  ushort*             eh    = (ushort*)((char*)d_ws + WS_EH);
  ushort*             em    = (ushort*)((char*)d_ws + WS_EM);
  ushort*             el    = (ushort*)((char*)d_ws + WS_EL);
  (void)in_sizes; (void)n_in; (void)out_size; (void)ws_size;

  hipMemsetAsync(d_ws, 0, 128, stream);                                  // acc+cnt
  hipMemsetAsync((char*)d_ws + WS_KEYS, 0xFF, (size_t)NR * 8, stream);   // keys
  hipMemsetAsync((char*)d_ws + WS_RISK, 0xFF, (size_t)NR * 4, stream);   // rmin keys

  k_znorm    <<<NR / 256, 256, 0, stream>>>(z, znorm);
  k_enorm    <<<KCB / 4, 256, 0, stream>>>(emb, enorm);
  k_transpose<<<(KCB / 64) * (CD / 64), 256, 0, stream>>>(emb, embt);
  k_esplit   <<<(KCB * CD) / 2048, 256, 0, stream>>>(emb, eh, em, el);
  k_dist_mfma<<<256, 512, 92160, stream>>>(z, eh, em, el, enorm, znorm, keys, risk);
  k_resolve  <<<NR / 256, 256, 0, stream>>>(keys, risk, idxA, list, cnt);
  k_rescan   <<<256, 256, 0, stream>>>(z, embt, enorm, znorm, list, cnt, idxA);
  k_gather   <<<NR / 16, 256, 0, stream>>>(z, emb, idxA, out, acc);
  k_loss     <<<1, 1, 0, stream>>>(acc, out);
}

// Round 7
// 1344.749 us; speedup vs baseline: 32.3532x; 1.0057x over previous
//
#include <hip/hip_runtime.h>

// VQ-VAE vector quantizer, MI355X round 7.
// bf16x3 6-chain MFMA distance GEMM with pre-split, swizzle-baked tiled
// operand planes staged via global_load_lds (2-phase double-buffered).
// Exact fp32-replication preserved by 2Sum midpoint-risk + r4-bit-identical
// fp32 rescan of flagged rows (machinery proven in r6, decisions unchanged).
// z: [2,512,8,32,32] fp32 ; emb: [8192,512] fp32
// out: z_q_ste (8388608 f32) | vq_loss (1 f32) | indices (16384 f32)

constexpr int KCB = 8192;
constexpr int CD  = 512;
constexpr int SD  = 8192;
constexpr int NB  = 2;
constexpr int NR  = NB * SD;                    // 16384
constexpr long ZQ_ELEMS = (long)NB * CD * SD;   // 8388608

constexpr size_t WS_CNT   = 64;
constexpr size_t WS_KEYS  = 128;       // u64 keys[16384]     -> 131200
constexpr size_t WS_RISK  = 139264;    // u32 rminKey[16384]  -> 204800
constexpr size_t WS_IDX   = 212992;    // int idxArr[16384]   -> 278528
constexpr size_t WS_LIST  = 286720;    // int list[16384]     -> 352256
constexpr size_t WS_ZNORM = 360448;    // f32 znorm[16384]    -> 425984
constexpr size_t WS_ENORM = 425984;    // f32 enorm[8192]     -> 458752
constexpr size_t WS_EMBT  = 458752;    // f32 embt            -> 17235968
constexpr size_t WS_ZH    = 17235968;  // bf16 z planes, tiled (16.8MB each)
constexpr size_t WS_ZM    = 34013184;
constexpr size_t WS_ZL    = 50790400;
constexpr size_t WS_EH    = 67567616;  // bf16 e planes, tiled (8.4MB each)
constexpr size_t WS_EM    = 75956224;
constexpr size_t WS_EL    = 84344832;  // -> 92733440 (~88.5MB)

#define RISK_EPS 2.0e-7f
#define WINDOW   1.3e-4f

typedef __attribute__((ext_vector_type(8))) short short8;
typedef __attribute__((ext_vector_type(4))) float f32x4;

__device__ __forceinline__ unsigned int fkey(float f) {
  unsigned int b = __float_as_uint(f);
  return (b & 0x80000000u) ? ~b : (b | 0x80000000u);
}
__device__ __forceinline__ float unfkey(unsigned int u) {
  return (u & 0x80000000u) ? __uint_as_float(u ^ 0x80000000u)
                           : __uint_as_float(~u);
}
__device__ __forceinline__ ushort bf16_rne(float f, float* back) {
  unsigned int u = __float_as_uint(f);
  ushort h = (ushort)((u + 0x7FFFu + ((u >> 16) & 1u)) >> 16);
  *back = __uint_as_float((unsigned int)h << 16);
  return h;
}
__device__ __forceinline__ void gload16(const void* g, void* l) {
  __builtin_amdgcn_global_load_lds(
      (const __attribute__((address_space(1))) unsigned int*)g,
      (__attribute__((address_space(3))) unsigned int*)l, 16, 0, 0);
}

// ---- znorm[n] = fp32(sum_c z[n][c]^2), fp64 accumulate ----
__global__ __launch_bounds__(256) void k_znorm(const float* __restrict__ z,
                                               float* __restrict__ znorm) {
  int n0 = blockIdx.x * 256;
  int b = n0 / SD, s0 = n0 % SD;
  const float* zp = z + (size_t)b * CD * SD + s0 + threadIdx.x;
  double a = 0.0;
  #pragma unroll 8
  for (int c = 0; c < CD; ++c) {
    double v = (double)zp[(size_t)c * SD];
    a = fma(v, v, a);
  }
  znorm[n0 + threadIdx.x] = (float)a;
}

// ---- enorm[k] ----
__global__ __launch_bounds__(256) void k_enorm(const float* __restrict__ emb,
                                               float* __restrict__ enorm) {
  int row  = blockIdx.x * 4 + (threadIdx.x >> 6);
  int lane = threadIdx.x & 63;
  const float4* p = (const float4*)(emb + (size_t)row * CD);
  float4 a = p[lane * 2], b = p[lane * 2 + 1];
  float s = a.x*a.x + a.y*a.y + a.z*a.z + a.w*a.w
          + b.x*b.x + b.y*b.y + b.z*b.z + b.w*b.w;
  #pragma unroll
  for (int off = 32; off; off >>= 1) s += __shfl_down(s, off);
  if (lane == 0) enorm[row] = s;
}

// ---- emb_t[c][k] = emb[k][c] (feeds the r4-identical rescan) ----
__global__ __launch_bounds__(256) void k_transpose(const float* __restrict__ emb,
                                                   float* __restrict__ embt) {
  __shared__ float t[64][65];
  int bk = blockIdx.x & 127, bc = blockIdx.x >> 7;
  int k0 = bk * 64, c0 = bc * 64;
  int t4 = threadIdx.x & 15, tq = threadIdx.x >> 4;
  #pragma unroll
  for (int p = 0; p < 4; ++p) {
    int kk = p * 16 + tq;
    float4 v = *(const float4*)(emb + (size_t)(k0 + kk) * CD + c0 + 4 * t4);
    t[kk][4*t4+0] = v.x; t[kk][4*t4+1] = v.y; t[kk][4*t4+2] = v.z; t[kk][4*t4+3] = v.w;
  }
  __syncthreads();
  #pragma unroll
  for (int p = 0; p < 4; ++p) {
    int cc = p * 16 + tq;
    float4 v;
    v.x = t[4*t4+0][cc]; v.y = t[4*t4+1][cc]; v.z = t[4*t4+2][cc]; v.w = t[4*t4+3][cc];
    *(float4*)(embt + (size_t)(c0 + cc) * KCB + k0 + 4 * t4) = v;
  }
}

// Tiled plane layout: tile = (row_tile rt, col_tile ct), 256 rows x 32 cols,
// 8192 ushorts. Element (r,c) at ushort offset r*32 + ((c>>3)^((r>>1)&3))*8
// + (c&7). Swizzle makes wave64 b128 fragment reads bank-conflict-free while
// global_load_lds stages the tile linearly (swizzle baked into global).

// ---- z [b][c][s] -> zh/zm/zl tiled planes (rows n = b*SD+s) ----
__global__ __launch_bounds__(256) void k_zsplit(const float* __restrict__ z,
                                                ushort* __restrict__ zh,
                                                ushort* __restrict__ zm,
                                                ushort* __restrict__ zl) {
  __shared__ float t[32][257];
  int rt = blockIdx.x >> 4, ct = blockIdx.x & 15;
  int n0 = rt * 256;
  int b = n0 >> 13, s0 = n0 & (SD - 1);
  const float* zp = z + (size_t)b * CD * SD + (size_t)(ct * 32) * SD + s0;
  #pragma unroll 4
  for (int c = 0; c < 32; ++c)
    t[c][threadIdx.x] = zp[(size_t)c * SD + threadIdx.x];
  __syncthreads();
  size_t tbase = ((size_t)rt * 16 + ct) * 8192;
  #pragma unroll
  for (int p = 0; p < 4; ++p) {
    int slot = p * 256 + threadIdx.x;
    int r = slot >> 2, cs = slot & 3;
    int csw = cs ^ ((r >> 1) & 3);
    union { ushort u[8]; int4 v; } ph, pm, pl;
    #pragma unroll
    for (int j = 0; j < 8; ++j) {
      float f = t[cs * 8 + j][r];
      float fh, fm, fl2;
      ph.u[j] = bf16_rne(f, &fh);
      float r1 = f - fh;
      pm.u[j] = bf16_rne(r1, &fm);
      float r2 = r1 - fm;
      pl.u[j] = bf16_rne(r2, &fl2);
    }
    size_t off = tbase + (size_t)r * 32 + csw * 8;
    *(int4*)(zh + off) = ph.v;
    *(int4*)(zm + off) = pm.v;
    *(int4*)(zl + off) = pl.v;
  }
}

// ---- emb [k][c] -> eh/em/el tiled planes ----
__global__ __launch_bounds__(256) void k_esplit(const float* __restrict__ emb,
                                                ushort* __restrict__ eh,
                                                ushort* __restrict__ em,
                                                ushort* __restrict__ el) {
  __shared__ float t[32][257];
  int rt = blockIdx.x >> 4, ct = blockIdx.x & 15;
  int k0 = rt * 256;
  #pragma unroll 4
  for (int i = 0; i < 32; ++i) {
    int idx = i * 256 + threadIdx.x;
    int r = idx >> 5, c = idx & 31;
    t[c][r] = emb[(size_t)(k0 + r) * CD + ct * 32 + c];
  }
  __syncthreads();
  size_t tbase = ((size_t)rt * 16 + ct) * 8192;
  #pragma unroll
  for (int p = 0; p < 4; ++p) {
    int slot = p * 256 + threadIdx.x;
    int r = slot >> 2, cs = slot & 3;
    int csw = cs ^ ((r >> 1) & 3);
    union { ushort u[8]; int4 v; } ph, pm, pl;
    #pragma unroll
    for (int j = 0; j < 8; ++j) {
      float f = t[cs * 8 + j][r];
      float fh, fm, fl2;
      ph.u[j] = bf16_rne(f, &fh);
      float r1 = f - fh;
      pm.u[j] = bf16_rne(r1, &fm);
      float r2 = r1 - fm;
      pl.u[j] = bf16_rne(r2, &fl2);
    }
    size_t off = tbase + (size_t)r * 32 + csw * 8;
    *(int4*)(eh + off) = ph.v;
    *(int4*)(em + off) = pm.v;
    *(int4*)(el + off) = pl.v;
  }
}

// ---- MFMA distance kernel: 2-phase double-buffered gload_lds staging ----
// 256 blocks x 512 thr (8 waves, 2Mx4N). Block: 128 m-rows x one khalf.
// LDS: A[2][3][8192B] @0 ; B[2][3][16384B] @49152 ; total 147456B.
__global__ __launch_bounds__(512, 2) void k_dist_mfma(
    const ushort* __restrict__ zh, const ushort* __restrict__ zm,
    const ushort* __restrict__ zl,
    const ushort* __restrict__ eh, const ushort* __restrict__ em,
    const ushort* __restrict__ el,
    const float* __restrict__ enorm, const float* __restrict__ znorm,
    unsigned long long* __restrict__ keys, unsigned int* __restrict__ riskArr) {
  extern __shared__ __align__(16) char smem[];

  int tid  = threadIdx.x;
  int lane = tid & 63;
  int wid  = tid >> 6;
  int wm = wid >> 2, wn = wid & 3;
  int lk = lane >> 4, lc = lane & 15;

  // bijective XCD swizzle (256 % 8 == 0): XCD x serves same-khalf m-groups
  int bid = (int)blockIdx.x;
  int swz = (bid & 7) * 32 + (bid >> 3);
  int m0    = (swz >> 1) * 128;
  int khalf = swz & 1;
  int n_rt  = m0 >> 8;
  int ahalf = (m0 >> 7) & 1;

  const ushort* apl[3] = {zh, zm, zl};
  const ushort* bpl[3] = {eh, em, el};

  float Aab[16];
  #pragma unroll
  for (int li = 0; li < 16; ++li)
    Aab[li] = znorm[m0 + wm * 64 + (li >> 2) * 16 + lk * 4 + (li & 3)];

  unsigned long long bkey[16];
  float rminv[16];
  #pragma unroll
  for (int li = 0; li < 16; ++li) { bkey[li] = ~0ull; rminv[li] = 3.402823466e38f; }

  auto stage = [&](int s, int bf) {
    int it = s >> 4, ks = s & 15;
    size_t aoff = ((size_t)(n_rt * 16 + ks)) * 8192 + ahalf * 4096 + (size_t)tid * 8;
    size_t boff = ((size_t)((khalf * 16 + it) * 16 + ks)) * 8192 + (size_t)tid * 8;
    #pragma unroll
    for (int p = 0; p < 3; ++p) {
      gload16(apl[p] + aoff, smem + bf * 24576 + p * 8192 + tid * 16);
      gload16(bpl[p] + boff, smem + 49152 + bf * 49152 + p * 16384 + tid * 16);
      gload16(bpl[p] + boff + 4096,
              smem + 49152 + bf * 49152 + p * 16384 + 8192 + tid * 16);
    }
  };

  f32x4 acc[4][4];
  stage(0, 0);

  for (int s = 0; s < 256; ++s) {
    int ks = s & 15, it = s >> 4, bf = s & 1;
    __syncthreads();                    // buf[bf] ready (vmcnt drained)
    if (s + 1 < 256) stage(s + 1, bf ^ 1);
    if (ks == 0) {
      #pragma unroll
      for (int mi = 0; mi < 4; ++mi)
        #pragma unroll
        for (int ni = 0; ni < 4; ++ni) {
          f32x4 zz = {0.f, 0.f, 0.f, 0.f};
          acc[mi][ni] = zz;
        }
    }
    const char* Ab = smem + bf * 24576;
    const char* Bb = smem + 49152 + bf * 49152;
    short8 a_h[4], a_m[4], a_l[4];
    #pragma unroll
    for (int mi = 0; mi < 4; ++mi) {
      int rowA = wm * 64 + mi * 16 + lc;
      int aoff = rowA * 64 + ((lk ^ ((rowA >> 1) & 3)) << 4);
      a_h[mi] = *(const short8*)(Ab + aoff);
      a_m[mi] = *(const short8*)(Ab + 8192 + aoff);
      a_l[mi] = *(const short8*)(Ab + 16384 + aoff);
    }
    #pragma unroll
    for (int ni = 0; ni < 4; ++ni) {
      int rowB = wn * 64 + ni * 16 + lc;
      int boff = rowB * 64 + ((lk ^ ((rowB >> 1) & 3)) << 4);
      short8 b_h = *(const short8*)(Bb + boff);
      short8 b_m = *(const short8*)(Bb + 16384 + boff);
      short8 b_l = *(const short8*)(Bb + 32768 + boff);
      #pragma unroll
      for (int mi = 0; mi < 4; ++mi)
        acc[mi][ni] = __builtin_amdgcn_mfma_f32_16x16x32_bf16(a_h[mi], b_h, acc[mi][ni], 0, 0, 0);
      #pragma unroll
      for (int mi = 0; mi < 4; ++mi)
        acc[mi][ni] = __builtin_amdgcn_mfma_f32_16x16x32_bf16(a_h[mi], b_m, acc[mi][ni], 0, 0, 0);
      #pragma unroll
      for (int mi = 0; mi < 4; ++mi)
        acc[mi][ni] = __builtin_amdgcn_mfma_f32_16x16x32_bf16(a_m[mi], b_h, acc[mi][ni], 0, 0, 0);
      #pragma unroll
      for (int mi = 0; mi < 4; ++mi)
        acc[mi][ni] = __builtin_amdgcn_mfma_f32_16x16x32_bf16(a_h[mi], b_l, acc[mi][ni], 0, 0, 0);
      #pragma unroll
      for (int mi = 0; mi < 4; ++mi)
        acc[mi][ni] = __builtin_amdgcn_mfma_f32_16x16x32_bf16(a_m[mi], b_m, acc[mi][ni], 0, 0, 0);
      #pragma unroll
      for (int mi = 0; mi < 4; ++mi)
        acc[mi][ni] = __builtin_amdgcn_mfma_f32_16x16x32_bf16(a_l[mi], b_h, acc[mi][ni], 0, 0, 0);
    }
    if (ks == 15) {
      int N0 = khalf * 4096 + it * 256;
      #pragma unroll
      for (int ni = 0; ni < 4; ++ni) {
        int col = N0 + wn * 64 + ni * 16 + lc;
        float en = enorm[col];
        #pragma unroll
        for (int mi = 0; mi < 4; ++mi) {
          #pragma unroll
          for (int r = 0; r < 4; ++r) {
            int li = mi * 4 + r;
            float ab = Aab[li] + en;
            float q  = -2.0f * acc[mi][ni][r];
            float sv = ab + q;
            float bvv = sv - ab;               // Fast2Sum: exact
            float t   = q - bvv;               // rounding residual
            unsigned int su = __float_as_uint(sv);
            float ulp = __uint_as_float(su & 0x7f800000u) * 1.1920929e-7f;
            bool risky = (0.5f * ulp - fabsf(t)) < RISK_EPS;
            if (((su & 0x7fffffu) == 0u) && (t < 0.f))
              risky |= ((0.25f * ulp + t) < RISK_EPS);
            unsigned long long key =
                ((unsigned long long)fkey(sv) << 32) | (unsigned int)col;
            if (key < bkey[li]) bkey[li] = key;
            if (risky && sv < rminv[li]) rminv[li] = sv;
          }
        }
      }
    }
  }
  // block reduction (reuse LDS)
  __syncthreads();
  unsigned long long* red = (unsigned long long*)smem;   // [128][64]
  #pragma unroll
  for (int li = 0; li < 16; ++li) {
    int row = wm * 64 + (li >> 2) * 16 + lk * 4 + (li & 3);
    red[row * 64 + wn * 16 + lc] = bkey[li];
  }
  __syncthreads();
  if (tid < 128) {
    unsigned long long mn = ~0ull;
    #pragma unroll 4
    for (int i = 0; i < 64; ++i) {
      unsigned long long v = red[tid * 64 + i];
      if (v < mn) mn = v;
    }
    atomicMin(&keys[m0 + tid], mn);
  }
  __syncthreads();
  unsigned int* red2 = (unsigned int*)smem;
  #pragma unroll
  for (int li = 0; li < 16; ++li) {
    int row = wm * 64 + (li >> 2) * 16 + lk * 4 + (li & 3);
    red2[row * 64 + wn * 16 + lc] = fkey(rminv[li]);
  }
  __syncthreads();
  if (tid < 128) {
    unsigned int mn = 0xFFFFFFFFu;
    #pragma unroll 4
    for (int i = 0; i < 64; ++i) {
      unsigned int v = red2[tid * 64 + i];
      if (v < mn) mn = v;
    }
    atomicMin(&riskArr[m0 + tid], mn);
  }
}

// ---- resolve: window test vs FINAL global min ----
__global__ __launch_bounds__(256) void k_resolve(const unsigned long long* __restrict__ keys,
                                                 const unsigned int* __restrict__ riskArr,
                                                 int* __restrict__ idxArr,
                                                 int* __restrict__ list,
                                                 unsigned int* __restrict__ cnt) {
  int row = blockIdx.x * 256 + threadIdx.x;
  unsigned long long kk = keys[row];
  idxArr[row] = (int)(kk & 0xffffffffull) & (KCB - 1);
  float smin = unfkey((unsigned int)(kk >> 32));
  float rmin = unfkey(riskArr[row]);          // NaN when no risky candidate
  if (rmin <= smin + WINDOW) {
    unsigned int pos = atomicAdd(cnt, 1u);
    list[pos & (NR - 1)] = row;
  }
}

// ---- rescan: bit-identical r4 fp32 path, 4-way ILP ----
__global__ __launch_bounds__(256) void k_rescan(const float* __restrict__ z,
                                                const float* __restrict__ embt,
                                                const float* __restrict__ enorm,
                                                const float* __restrict__ znorm,
                                                const int* __restrict__ list,
                                                const unsigned int* __restrict__ cnt,
                                                int* __restrict__ idxArr) {
  __shared__ float zs[512];
  __shared__ unsigned long long rk[256];
  int tid = threadIdx.x;
  unsigned int nr = *cnt;
  if (nr > (unsigned int)NR) nr = NR;
  for (unsigned int li = blockIdx.x; li < nr; li += gridDim.x) {
    int row = list[li] & (NR - 1);
    int b = row >> 13, s = row & (SD - 1);
    const float* zp = z + (size_t)b * CD * SD + s;
    zs[tid]       = zp[(size_t)tid * SD];
    zs[tid + 256] = zp[(size_t)(tid + 256) * SD];
    __syncthreads();
    float A = znorm[row];
    unsigned long long best = ~0ull;
    #pragma unroll 1
    for (int g = 0; g < 8; ++g) {
      int ka = tid + g * 1024;
      float a0 = 0.f, a1 = 0.f, a2 = 0.f, a3 = 0.f;
      #pragma unroll 8
      for (int c = 0; c < CD; ++c) {          // ascending c: r4's exact order
        const float* ep = embt + (size_t)c * KCB + ka;
        float zc = zs[c];
        a0 = fmaf(zc, ep[0],   a0);
        a1 = fmaf(zc, ep[256], a1);
        a2 = fmaf(zc, ep[512], a2);
        a3 = fmaf(zc, ep[768], a3);
      }
      float av[4] = {a0, a1, a2, a3};
      #pragma unroll
      for (int jj = 0; jj < 4; ++jj) {
        int k = ka + jj * 256;
        float d = (A + enorm[k]) - 2.0f * av[jj];   // identical to r4
        unsigned long long key =
            ((unsigned long long)fkey(d) << 32) | (unsigned int)k;
        if (key < best) best = key;
      }
    }
    rk[tid] = best;
    __syncthreads();
    for (int s2 = 128; s2; s2 >>= 1) {
      if (tid < s2 && rk[tid + s2] < rk[tid]) rk[tid] = rk[tid + s2];
      __syncthreads();
    }
    if (tid == 0) idxArr[row] = (int)(rk[0] & 0xffffffffull) & (KCB - 1);
    __syncthreads();
  }
}

// ---- gather + STE + mse partial ----
__global__ __launch_bounds__(256) void k_gather(const float* __restrict__ z,
                                                const float* __restrict__ emb,
                                                const int* __restrict__ idxArr,
                                                float* __restrict__ out,
                                                double* __restrict__ acc) {
  __shared__ float q[16][516];
  __shared__ int   idxs[16];
  __shared__ float wpart[4];
  int tid = threadIdx.x;
  int n0 = blockIdx.x * 16;
  int b = n0 / SD, s0 = n0 % SD;
  if (tid < 16) {
    int idx = idxArr[n0 + tid] & (KCB - 1);
    idxs[tid] = idx;
    out[ZQ_ELEMS + 1 + n0 + tid] = (float)idx;
  }
  __syncthreads();
  int row = tid >> 4, c4 = (tid & 15) * 4;
  const float* esrc = emb + (size_t)idxs[row] * CD;
  #pragma unroll
  for (int p = 0; p < 8; ++p) {
    int c = c4 + p * 64;
    *(float4*)&q[row][c] = *(const float4*)(esrc + c);
  }
  __syncthreads();
  int si = tid & 15, cq = tid >> 4;
  float sum = 0.f;
  const float* zrd = z   + (size_t)b * CD * SD + s0 + si;
  float*       owr = out + (size_t)b * CD * SD + s0 + si;
  #pragma unroll
  for (int j = 0; j < 32; ++j) {
    int c = cq + 16 * j;
    float zv = zrd[(size_t)c * SD];
    float qv = q[si][c];
    float d = qv - zv;
    sum += d * d;
    owr[(size_t)c * SD] = zv + (qv - zv);
  }
  #pragma unroll
  for (int off = 32; off; off >>= 1) sum += __shfl_down(sum, off);
  if ((tid & 63) == 0) wpart[tid >> 6] = sum;
  __syncthreads();
  if (tid == 0) {
    double t = (double)wpart[0] + (double)wpart[1] + (double)wpart[2] + (double)wpart[3];
    atomicAdd(acc, t);
  }
}

__global__ void k_loss(const double* __restrict__ acc, float* __restrict__ out) {
  out[ZQ_ELEMS] = (float)(1.25 * (*acc) / (double)ZQ_ELEMS);
}

extern "C" void kernel_launch(void* const* d_in, const int* in_sizes, int n_in,
                              void* d_out, int out_size, void* d_ws, size_t ws_size,
                              hipStream_t stream) {
  const float* z   = (const float*)d_in[0];
  const float* emb = (const float*)d_in[1];
  float* out = (float*)d_out;
  double*             acc   = (double*)d_ws;
  unsigned int*       cnt   = (unsigned int*)((char*)d_ws + WS_CNT);
  unsigned long long* keys  = (unsigned long long*)((char*)d_ws + WS_KEYS);
  unsigned int*       risk  = (unsigned int*)((char*)d_ws + WS_RISK);
  int*                idxA  = (int*)((char*)d_ws + WS_IDX);
  int*                list  = (int*)((char*)d_ws + WS_LIST);
  float*              znorm = (float*)((char*)d_ws + WS_ZNORM);
  float*              enorm = (float*)((char*)d_ws + WS_ENORM);
  float*              embt  = (float*)((char*)d_ws + WS_EMBT);
  ushort* zh = (ushort*)((char*)d_ws + WS_ZH);
  ushort* zm = (ushort*)((char*)d_ws + WS_ZM);
  ushort* zl = (ushort*)((char*)d_ws + WS_ZL);
  ushort* eh = (ushort*)((char*)d_ws + WS_EH);
  ushort* em = (ushort*)((char*)d_ws + WS_EM);
  ushort* el = (ushort*)((char*)d_ws + WS_EL);
  (void)in_sizes; (void)n_in; (void)out_size; (void)ws_size;

  hipMemsetAsync(d_ws, 0, 128, stream);                                  // acc+cnt
  hipMemsetAsync((char*)d_ws + WS_KEYS, 0xFF, (size_t)NR * 8, stream);   // keys
  hipMemsetAsync((char*)d_ws + WS_RISK, 0xFF, (size_t)NR * 4, stream);   // rmin keys

  k_znorm    <<<NR / 256, 256, 0, stream>>>(z, znorm);
  k_enorm    <<<KCB / 4, 256, 0, stream>>>(emb, enorm);
  k_transpose<<<(KCB / 64) * (CD / 64), 256, 0, stream>>>(emb, embt);
  k_zsplit   <<<(NR / 256) * 16, 256, 0, stream>>>(z, zh, zm, zl);
  k_esplit   <<<(KCB / 256) * 16, 256, 0, stream>>>(emb, eh, em, el);
  k_dist_mfma<<<256, 512, 147456, stream>>>(zh, zm, zl, eh, em, el,
                                            enorm, znorm, keys, risk);
  k_resolve  <<<NR / 256, 256, 0, stream>>>(keys, risk, idxA, list, cnt);
  k_rescan   <<<256, 256, 0, stream>>>(z, embt, enorm, znorm, list, cnt, idxA);
  k_gather   <<<NR / 16, 256, 0, stream>>>(z, emb, idxA, out, acc);
  k_loss     <<<1, 1, 0, stream>>>(acc, out);
}

// Round 8
// 907.826 us; speedup vs baseline: 47.9243x; 1.4813x over previous
//
#include <hip/hip_runtime.h>

// VQ-VAE vector quantizer, MI355X round 8.
// = round 7 (pre-split swizzle-baked planes + global_load_lds 2-phase dbuf)
// with the r6 two-level loop structure to eliminate hot-loop scratch spills
// (r7: WRITE_SIZE 702MB of spill traffic at VGPR 128). Operand values and
// MFMA chain order are bit-identical to r6/r7 -> decisions unchanged; risk
// + r4-bit-identical rescan machinery proven (absmax 0 in r6 and r7).
// z: [2,512,8,32,32] fp32 ; emb: [8192,512] fp32
// out: z_q_ste (8388608 f32) | vq_loss (1 f32) | indices (16384 f32)

constexpr int KCB = 8192;
constexpr int CD  = 512;
constexpr int SD  = 8192;
constexpr int NB  = 2;
constexpr int NR  = NB * SD;                    // 16384
constexpr long ZQ_ELEMS = (long)NB * CD * SD;   // 8388608

constexpr size_t WS_CNT   = 64;
constexpr size_t WS_KEYS  = 128;       // u64 keys[16384]     -> 131200
constexpr size_t WS_RISK  = 139264;    // u32 rminKey[16384]  -> 204800
constexpr size_t WS_IDX   = 212992;    // int idxArr[16384]   -> 278528
constexpr size_t WS_LIST  = 286720;    // int list[16384]     -> 352256
constexpr size_t WS_ZNORM = 360448;    // f32 znorm[16384]    -> 425984
constexpr size_t WS_ENORM = 425984;    // f32 enorm[8192]     -> 458752
constexpr size_t WS_EMBT  = 458752;    // f32 embt            -> 17235968
constexpr size_t WS_ZH    = 17235968;  // bf16 z planes, tiled
constexpr size_t WS_ZM    = 34013184;
constexpr size_t WS_ZL    = 50790400;
constexpr size_t WS_EH    = 67567616;  // bf16 e planes, tiled
constexpr size_t WS_EM    = 75956224;
constexpr size_t WS_EL    = 84344832;  // -> 92733440 (~88.5MB)

#define RISK_EPS 2.0e-7f
#define WINDOW   1.3e-4f

typedef __attribute__((ext_vector_type(8))) short short8;
typedef __attribute__((ext_vector_type(4))) float f32x4;

__device__ __forceinline__ unsigned int fkey(float f) {
  unsigned int b = __float_as_uint(f);
  return (b & 0x80000000u) ? ~b : (b | 0x80000000u);
}
__device__ __forceinline__ float unfkey(unsigned int u) {
  return (u & 0x80000000u) ? __uint_as_float(u ^ 0x80000000u)
                           : __uint_as_float(~u);
}
__device__ __forceinline__ ushort bf16_rne(float f, float* back) {
  unsigned int u = __float_as_uint(f);
  ushort h = (ushort)((u + 0x7FFFu + ((u >> 16) & 1u)) >> 16);
  *back = __uint_as_float((unsigned int)h << 16);
  return h;
}
__device__ __forceinline__ void gload16(const void* g, void* l) {
  __builtin_amdgcn_global_load_lds(
      (const __attribute__((address_space(1))) unsigned int*)g,
      (__attribute__((address_space(3))) unsigned int*)l, 16, 0, 0);
}

// ---- znorm[n] = fp32(sum_c z[n][c]^2), fp64 accumulate ----
__global__ __launch_bounds__(256) void k_znorm(const float* __restrict__ z,
                                               float* __restrict__ znorm) {
  int n0 = blockIdx.x * 256;
  int b = n0 / SD, s0 = n0 % SD;
  const float* zp = z + (size_t)b * CD * SD + s0 + threadIdx.x;
  double a = 0.0;
  #pragma unroll 8
  for (int c = 0; c < CD; ++c) {
    double v = (double)zp[(size_t)c * SD];
    a = fma(v, v, a);
  }
  znorm[n0 + threadIdx.x] = (float)a;
}

// ---- enorm[k] ----
__global__ __launch_bounds__(256) void k_enorm(const float* __restrict__ emb,
                                               float* __restrict__ enorm) {
  int row  = blockIdx.x * 4 + (threadIdx.x >> 6);
  int lane = threadIdx.x & 63;
  const float4* p = (const float4*)(emb + (size_t)row * CD);
  float4 a = p[lane * 2], b = p[lane * 2 + 1];
  float s = a.x*a.x + a.y*a.y + a.z*a.z + a.w*a.w
          + b.x*b.x + b.y*b.y + b.z*b.z + b.w*b.w;
  #pragma unroll
  for (int off = 32; off; off >>= 1) s += __shfl_down(s, off);
  if (lane == 0) enorm[row] = s;
}

// ---- emb_t[c][k] = emb[k][c] (feeds the r4-identical rescan) ----
__global__ __launch_bounds__(256) void k_transpose(const float* __restrict__ emb,
                                                   float* __restrict__ embt) {
  __shared__ float t[64][65];
  int bk = blockIdx.x & 127, bc = blockIdx.x >> 7;
  int k0 = bk * 64, c0 = bc * 64;
  int t4 = threadIdx.x & 15, tq = threadIdx.x >> 4;
  #pragma unroll
  for (int p = 0; p < 4; ++p) {
    int kk = p * 16 + tq;
    float4 v = *(const float4*)(emb + (size_t)(k0 + kk) * CD + c0 + 4 * t4);
    t[kk][4*t4+0] = v.x; t[kk][4*t4+1] = v.y; t[kk][4*t4+2] = v.z; t[kk][4*t4+3] = v.w;
  }
  __syncthreads();
  #pragma unroll
  for (int p = 0; p < 4; ++p) {
    int cc = p * 16 + tq;
    float4 v;
    v.x = t[4*t4+0][cc]; v.y = t[4*t4+1][cc]; v.z = t[4*t4+2][cc]; v.w = t[4*t4+3][cc];
    *(float4*)(embt + (size_t)(c0 + cc) * KCB + k0 + 4 * t4) = v;
  }
}

// Tiled plane layout (r7-proven): tile (rt,ct) = 256 rows x 32 cols, 8192
// ushorts at (rt*16+ct)*8192. Element (r,c) at r*32 + ((c>>3)^((r>>1)&3))*8
// + (c&7): wave64 b128 fragment reads are bank-conflict-free while
// global_load_lds stages linearly (swizzle baked into global layout).

// ---- z [b][c][s] -> zh/zm/zl tiled planes ----
__global__ __launch_bounds__(256) void k_zsplit(const float* __restrict__ z,
                                                ushort* __restrict__ zh,
                                                ushort* __restrict__ zm,
                                                ushort* __restrict__ zl) {
  __shared__ float t[32][257];
  int rt = blockIdx.x >> 4, ct = blockIdx.x & 15;
  int n0 = rt * 256;
  int b = n0 >> 13, s0 = n0 & (SD - 1);
  const float* zp = z + (size_t)b * CD * SD + (size_t)(ct * 32) * SD + s0;
  #pragma unroll 4
  for (int c = 0; c < 32; ++c)
    t[c][threadIdx.x] = zp[(size_t)c * SD + threadIdx.x];
  __syncthreads();
  size_t tbase = ((size_t)rt * 16 + ct) * 8192;
  #pragma unroll
  for (int p = 0; p < 4; ++p) {
    int slot = p * 256 + threadIdx.x;
    int r = slot >> 2, cs = slot & 3;
    int csw = cs ^ ((r >> 1) & 3);
    union { ushort u[8]; int4 v; } ph, pm, pl;
    #pragma unroll
    for (int j = 0; j < 8; ++j) {
      float f = t[cs * 8 + j][r];
      float fh, fm, fl2;
      ph.u[j] = bf16_rne(f, &fh);
      float r1 = f - fh;
      pm.u[j] = bf16_rne(r1, &fm);
      float r2 = r1 - fm;
      pl.u[j] = bf16_rne(r2, &fl2);
    }
    size_t off = tbase + (size_t)r * 32 + csw * 8;
    *(int4*)(zh + off) = ph.v;
    *(int4*)(zm + off) = pm.v;
    *(int4*)(zl + off) = pl.v;
  }
}

// ---- emb [k][c] -> eh/em/el tiled planes ----
__global__ __launch_bounds__(256) void k_esplit(const float* __restrict__ emb,
                                                ushort* __restrict__ eh,
                                                ushort* __restrict__ em,
                                                ushort* __restrict__ el) {
  __shared__ float t[32][257];
  int rt = blockIdx.x >> 4, ct = blockIdx.x & 15;
  int k0 = rt * 256;
  #pragma unroll 4
  for (int i = 0; i < 32; ++i) {
    int idx = i * 256 + threadIdx.x;
    int r = idx >> 5, c = idx & 31;
    t[c][r] = emb[(size_t)(k0 + r) * CD + ct * 32 + c];
  }
  __syncthreads();
  size_t tbase = ((size_t)rt * 16 + ct) * 8192;
  #pragma unroll
  for (int p = 0; p < 4; ++p) {
    int slot = p * 256 + threadIdx.x;
    int r = slot >> 2, cs = slot & 3;
    int csw = cs ^ ((r >> 1) & 3);
    union { ushort u[8]; int4 v; } ph, pm, pl;
    #pragma unroll
    for (int j = 0; j < 8; ++j) {
      float f = t[cs * 8 + j][r];
      float fh, fm, fl2;
      ph.u[j] = bf16_rne(f, &fh);
      float r1 = f - fh;
      pm.u[j] = bf16_rne(r1, &fm);
      float r2 = r1 - fm;
      pl.u[j] = bf16_rne(r2, &fl2);
    }
    size_t off = tbase + (size_t)r * 32 + csw * 8;
    *(int4*)(eh + off) = ph.v;
    *(int4*)(em + off) = pm.v;
    *(int4*)(el + off) = pl.v;
  }
}

// ---- MFMA distance kernel: 2-phase dbuf gload_lds, spill-free structure ----
// 256 blocks x 512 thr (8 waves, 2Mx4N). Block: 128 m-rows x one khalf.
// LDS: A[2][3][8192B] @0 ; B[2][3][16384B] @49152 ; total 147456B.
__global__ __launch_bounds__(512, 2) void k_dist_mfma(
    const ushort* __restrict__ zh, const ushort* __restrict__ zm,
    const ushort* __restrict__ zl,
    const ushort* __restrict__ eh, const ushort* __restrict__ em,
    const ushort* __restrict__ el,
    const float* __restrict__ enorm, const float* __restrict__ znorm,
    unsigned long long* __restrict__ keys, unsigned int* __restrict__ riskArr) {
  extern __shared__ __align__(16) char smem[];

  int tid  = threadIdx.x;
  int lane = tid & 63;
  int wid  = tid >> 6;
  int wm = wid >> 2, wn = wid & 3;
  int lk = lane >> 4, lc = lane & 15;

  // bijective XCD swizzle (256 % 8 == 0)
  int bid = (int)blockIdx.x;
  int swz = (bid & 7) * 32 + (bid >> 3);
  int m0    = (swz >> 1) * 128;
  int khalf = swz & 1;
  int n_rt  = m0 >> 8;
  int ahalf = (m0 >> 7) & 1;

  // persistent per-thread staging pointers (element offsets baked in)
  size_t abase = (size_t)(n_rt * 16) * 8192 + (size_t)ahalf * 4096 + (size_t)tid * 8;
  size_t bbase = (size_t)(khalf * 256) * 8192 + (size_t)tid * 8;
  const ushort* a0 = zh + abase;
  const ushort* a1 = zm + abase;
  const ushort* a2 = zl + abase;
  const ushort* b0 = eh + bbase;
  const ushort* b1 = em + bbase;
  const ushort* b2 = el + bbase;
  char* lA = smem + (size_t)tid * 16;
  char* lB = smem + 49152 + (size_t)tid * 16;

  // loop-invariant fragment LDS byte offsets
  int afo[4], bfo[4];
  #pragma unroll
  for (int mi = 0; mi < 4; ++mi) {
    int rowA = wm * 64 + mi * 16 + lc;
    afo[mi] = rowA * 64 + ((lk ^ ((rowA >> 1) & 3)) << 4);
  }
  #pragma unroll
  for (int ni = 0; ni < 4; ++ni) {
    int rowB = wn * 64 + ni * 16 + lc;
    bfo[ni] = rowB * 64 + ((lk ^ ((rowB >> 1) & 3)) << 4);
  }

  unsigned long long bkey[16];
  float rminv[16];
  #pragma unroll
  for (int li = 0; li < 16; ++li) { bkey[li] = ~0ull; rminv[li] = 3.402823466e38f; }

#define STAGE(s_) do {                                                  \
    int bf_ = (s_) & 1;                                                 \
    size_t ae_ = (size_t)((s_) & 15) * 8192;                            \
    size_t be_ = (size_t)(s_) * 8192;                                   \
    gload16(a0 + ae_, lA + bf_ * 24576);                                \
    gload16(a1 + ae_, lA + bf_ * 24576 + 8192);                         \
    gload16(a2 + ae_, lA + bf_ * 24576 + 16384);                        \
    gload16(b0 + be_,        lB + bf_ * 49152);                         \
    gload16(b0 + be_ + 4096, lB + bf_ * 49152 + 8192);                  \
    gload16(b1 + be_,        lB + bf_ * 49152 + 16384);                 \
    gload16(b1 + be_ + 4096, lB + bf_ * 49152 + 24576);                 \
    gload16(b2 + be_,        lB + bf_ * 49152 + 32768);                 \
    gload16(b2 + be_ + 4096, lB + bf_ * 49152 + 40960);                 \
  } while (0)

  STAGE(0);

  for (int it = 0; it < 16; ++it) {
    f32x4 acc[4][4];
    #pragma unroll
    for (int mi = 0; mi < 4; ++mi)
      #pragma unroll
      for (int ni = 0; ni < 4; ++ni) {
        f32x4 zz = {0.f, 0.f, 0.f, 0.f};
        acc[mi][ni] = zz;
      }

    for (int ks = 0; ks < 16; ++ks) {
      int s = it * 16 + ks;
      int bf = s & 1;
      __syncthreads();                 // buf[bf] ready; prev compute done
      if (s < 255) STAGE(s + 1);       // fill buf[bf^1]
      const char* Ab = smem + bf * 24576;
      const char* Bb = smem + 49152 + bf * 49152;
      short8 a_h[4], a_m[4], a_l[4];
      #pragma unroll
      for (int mi = 0; mi < 4; ++mi) {
        a_h[mi] = *(const short8*)(Ab + afo[mi]);
        a_m[mi] = *(const short8*)(Ab + 8192 + afo[mi]);
        a_l[mi] = *(const short8*)(Ab + 16384 + afo[mi]);
      }
      #pragma unroll
      for (int ni = 0; ni < 4; ++ni) {
        short8 b_h = *(const short8*)(Bb + bfo[ni]);
        short8 b_m = *(const short8*)(Bb + 16384 + bfo[ni]);
        short8 b_l = *(const short8*)(Bb + 32768 + bfo[ni]);
        #pragma unroll
        for (int mi = 0; mi < 4; ++mi)
          acc[mi][ni] = __builtin_amdgcn_mfma_f32_16x16x32_bf16(a_h[mi], b_h, acc[mi][ni], 0, 0, 0);
        #pragma unroll
        for (int mi = 0; mi < 4; ++mi)
          acc[mi][ni] = __builtin_amdgcn_mfma_f32_16x16x32_bf16(a_h[mi], b_m, acc[mi][ni], 0, 0, 0);
        #pragma unroll
        for (int mi = 0; mi < 4; ++mi)
          acc[mi][ni] = __builtin_amdgcn_mfma_f32_16x16x32_bf16(a_m[mi], b_h, acc[mi][ni], 0, 0, 0);
        #pragma unroll
        for (int mi = 0; mi < 4; ++mi)
          acc[mi][ni] = __builtin_amdgcn_mfma_f32_16x16x32_bf16(a_h[mi], b_l, acc[mi][ni], 0, 0, 0);
        #pragma unroll
        for (int mi = 0; mi < 4; ++mi)
          acc[mi][ni] = __builtin_amdgcn_mfma_f32_16x16x32_bf16(a_m[mi], b_m, acc[mi][ni], 0, 0, 0);
        #pragma unroll
        for (int mi = 0; mi < 4; ++mi)
          acc[mi][ni] = __builtin_amdgcn_mfma_f32_16x16x32_bf16(a_l[mi], b_h, acc[mi][ni], 0, 0, 0);
      }
    }

    // per-it epilogue (outside inner loop: keeps hot-loop pressure low)
    int N0 = khalf * 4096 + it * 256;
    #pragma unroll
    for (int ni = 0; ni < 4; ++ni) {
      int col = N0 + wn * 64 + ni * 16 + lc;
      float en = enorm[col];
      #pragma unroll
      for (int mi = 0; mi < 4; ++mi) {
        #pragma unroll
        for (int r = 0; r < 4; ++r) {
          int li = mi * 4 + r;
          float A  = znorm[m0 + wm * 64 + mi * 16 + lk * 4 + r];
          float ab = A + en;
          float q  = -2.0f * acc[mi][ni][r];
          float sv = ab + q;
          float bvv = sv - ab;               // Fast2Sum: exact
          float t   = q - bvv;               // rounding residual
          unsigned int su = __float_as_uint(sv);
          float ulp = __uint_as_float(su & 0x7f800000u) * 1.1920929e-7f;
          bool risky = (0.5f * ulp - fabsf(t)) < RISK_EPS;
          if (((su & 0x7fffffu) == 0u) && (t < 0.f))
            risky |= ((0.25f * ulp + t) < RISK_EPS);
          unsigned long long key =
              ((unsigned long long)fkey(sv) << 32) | (unsigned int)col;
          if (key < bkey[li]) bkey[li] = key;
          if (risky && sv < rminv[li]) rminv[li] = sv;
        }
      }
    }
  }
#undef STAGE

  // block reduction (reuse LDS)
  __syncthreads();
  unsigned long long* red = (unsigned long long*)smem;   // [128][64]
  #pragma unroll
  for (int li = 0; li < 16; ++li) {
    int row = wm * 64 + (li >> 2) * 16 + lk * 4 + (li & 3);
    red[row * 64 + wn * 16 + lc] = bkey[li];
  }
  __syncthreads();
  if (tid < 128) {
    unsigned long long mn = ~0ull;
    #pragma unroll 4
    for (int i = 0; i < 64; ++i) {
      unsigned long long v = red[tid * 64 + i];
      if (v < mn) mn = v;
    }
    atomicMin(&keys[m0 + tid], mn);
  }
  __syncthreads();
  unsigned int* red2 = (unsigned int*)smem;
  #pragma unroll
  for (int li = 0; li < 16; ++li) {
    int row = wm * 64 + (li >> 2) * 16 + lk * 4 + (li & 3);
    red2[row * 64 + wn * 16 + lc] = fkey(rminv[li]);
  }
  __syncthreads();
  if (tid < 128) {
    unsigned int mn = 0xFFFFFFFFu;
    #pragma unroll 4
    for (int i = 0; i < 64; ++i) {
      unsigned int v = red2[tid * 64 + i];
      if (v < mn) mn = v;
    }
    atomicMin(&riskArr[m0 + tid], mn);
  }
}

// ---- resolve: window test vs FINAL global min ----
__global__ __launch_bounds__(256) void k_resolve(const unsigned long long* __restrict__ keys,
                                                 const unsigned int* __restrict__ riskArr,
                                                 int* __restrict__ idxArr,
                                                 int* __restrict__ list,
                                                 unsigned int* __restrict__ cnt) {
  int row = blockIdx.x * 256 + threadIdx.x;
  unsigned long long kk = keys[row];
  idxArr[row] = (int)(kk & 0xffffffffull) & (KCB - 1);
  float smin = unfkey((unsigned int)(kk >> 32));
  float rmin = unfkey(riskArr[row]);          // NaN when no risky candidate
  if (rmin <= smin + WINDOW) {
    unsigned int pos = atomicAdd(cnt, 1u);
    list[pos & (NR - 1)] = row;
  }
}

// ---- rescan: bit-identical r4 fp32 path, 4-way ILP ----
__global__ __launch_bounds__(256) void k_rescan(const float* __restrict__ z,
                                                const float* __restrict__ embt,
                                                const float* __restrict__ enorm,
                                                const float* __restrict__ znorm,
                                                const int* __restrict__ list,
                                                const unsigned int* __restrict__ cnt,
                                                int* __restrict__ idxArr) {
  __shared__ float zs[512];
  __shared__ unsigned long long rk[256];
  int tid = threadIdx.x;
  unsigned int nr = *cnt;
  if (nr > (unsigned int)NR) nr = NR;
  for (unsigned int li = blockIdx.x; li < nr; li += gridDim.x) {
    int row = list[li] & (NR - 1);
    int b = row >> 13, s = row & (SD - 1);
    const float* zp = z + (size_t)b * CD * SD + s;
    zs[tid]       = zp[(size_t)tid * SD];
    zs[tid + 256] = zp[(size_t)(tid + 256) * SD];
    __syncthreads();
    float A = znorm[row];
    unsigned long long best = ~0ull;
    #pragma unroll 1
    for (int g = 0; g < 8; ++g) {
      int ka = tid + g * 1024;
      float a0 = 0.f, a1 = 0.f, a2 = 0.f, a3 = 0.f;
      #pragma unroll 8
      for (int c = 0; c < CD; ++c) {          // ascending c: r4's exact order
        const float* ep = embt + (size_t)c * KCB + ka;
        float zc = zs[c];
        a0 = fmaf(zc, ep[0],   a0);
        a1 = fmaf(zc, ep[256], a1);
        a2 = fmaf(zc, ep[512], a2);
        a3 = fmaf(zc, ep[768], a3);
      }
      float av[4] = {a0, a1, a2, a3};
      #pragma unroll
      for (int jj = 0; jj < 4; ++jj) {
        int k = ka + jj * 256;
        float d = (A + enorm[k]) - 2.0f * av[jj];   // identical to r4
        unsigned long long key =
            ((unsigned long long)fkey(d) << 32) | (unsigned int)k;
        if (key < best) best = key;
      }
    }
    rk[tid] = best;
    __syncthreads();
    for (int s2 = 128; s2; s2 >>= 1) {
      if (tid < s2 && rk[tid + s2] < rk[tid]) rk[tid] = rk[tid + s2];
      __syncthreads();
    }
    if (tid == 0) idxArr[row] = (int)(rk[0] & 0xffffffffull) & (KCB - 1);
    __syncthreads();
  }
}

// ---- gather + STE + mse partial ----
__global__ __launch_bounds__(256) void k_gather(const float* __restrict__ z,
                                                const float* __restrict__ emb,
                                                const int* __restrict__ idxArr,
                                                float* __restrict__ out,
                                                double* __restrict__ acc) {
  __shared__ float q[16][516];
  __shared__ int   idxs[16];
  __shared__ float wpart[4];
  int tid = threadIdx.x;
  int n0 = blockIdx.x * 16;
  int b = n0 / SD, s0 = n0 % SD;
  if (tid < 16) {
    int idx = idxArr[n0 + tid] & (KCB - 1);
    idxs[tid] = idx;
    out[ZQ_ELEMS + 1 + n0 + tid] = (float)idx;
  }
  __syncthreads();
  int row = tid >> 4, c4 = (tid & 15) * 4;
  const float* esrc = emb + (size_t)idxs[row] * CD;
  #pragma unroll
  for (int p = 0; p < 8; ++p) {
    int c = c4 + p * 64;
    *(float4*)&q[row][c] = *(const float4*)(esrc + c);
  }
  __syncthreads();
  int si = tid & 15, cq = tid >> 4;
  float sum = 0.f;
  const float* zrd = z   + (size_t)b * CD * SD + s0 + si;
  float*       owr = out + (size_t)b * CD * SD + s0 + si;
  #pragma unroll
  for (int j = 0; j < 32; ++j) {
    int c = cq + 16 * j;
    float zv = zrd[(size_t)c * SD];
    float qv = q[si][c];
    float d = qv - zv;
    sum += d * d;
    owr[(size_t)c * SD] = zv + (qv - zv);
  }
  #pragma unroll
  for (int off = 32; off; off >>= 1) sum += __shfl_down(sum, off);
  if ((tid & 63) == 0) wpart[tid >> 6] = sum;
  __syncthreads();
  if (tid == 0) {
    double t = (double)wpart[0] + (double)wpart[1] + (double)wpart[2] + (double)wpart[3];
    atomicAdd(acc, t);
  }
}

__global__ void k_loss(const double* __restrict__ acc, float* __restrict__ out) {
  out[ZQ_ELEMS] = (float)(1.25 * (*acc) / (double)ZQ_ELEMS);
}

extern "C" void kernel_launch(void* const* d_in, const int* in_sizes, int n_in,
                              void* d_out, int out_size, void* d_ws, size_t ws_size,
                              hipStream_t stream) {
  const float* z   = (const float*)d_in[0];
  const float* emb = (const float*)d_in[1];
  float* out = (float*)d_out;
  double*             acc   = (double*)d_ws;
  unsigned int*       cnt   = (unsigned int*)((char*)d_ws + WS_CNT);
  unsigned long long* keys  = (unsigned long long*)((char*)d_ws + WS_KEYS);
  unsigned int*       risk  = (unsigned int*)((char*)d_ws + WS_RISK);
  int*                idxA  = (int*)((char*)d_ws + WS_IDX);
  int*                list  = (int*)((char*)d_ws + WS_LIST);
  float*              znorm = (float*)((char*)d_ws + WS_ZNORM);
  float*              enorm = (float*)((char*)d_ws + WS_ENORM);
  float*              embt  = (float*)((char*)d_ws + WS_EMBT);
  ushort* zh = (ushort*)((char*)d_ws + WS_ZH);
  ushort* zm = (ushort*)((char*)d_ws + WS_ZM);
  ushort* zl = (ushort*)((char*)d_ws + WS_ZL);
  ushort* eh = (ushort*)((char*)d_ws + WS_EH);
  ushort* em = (ushort*)((char*)d_ws + WS_EM);
  ushort* el = (ushort*)((char*)d_ws + WS_EL);
  (void)in_sizes; (void)n_in; (void)out_size; (void)ws_size;

  hipMemsetAsync(d_ws, 0, 128, stream);                                  // acc+cnt
  hipMemsetAsync((char*)d_ws + WS_KEYS, 0xFF, (size_t)NR * 8, stream);   // keys
  hipMemsetAsync((char*)d_ws + WS_RISK, 0xFF, (size_t)NR * 4, stream);   // rmin keys

  k_znorm    <<<NR / 256, 256, 0, stream>>>(z, znorm);
  k_enorm    <<<KCB / 4, 256, 0, stream>>>(emb, enorm);
  k_transpose<<<(KCB / 64) * (CD / 64), 256, 0, stream>>>(emb, embt);
  k_zsplit   <<<(NR / 256) * 16, 256, 0, stream>>>(z, zh, zm, zl);
  k_esplit   <<<(KCB / 256) * 16, 256, 0, stream>>>(emb, eh, em, el);
  k_dist_mfma<<<256, 512, 147456, stream>>>(zh, zm, zl, eh, em, el,
                                            enorm, znorm, keys, risk);
  k_resolve  <<<NR / 256, 256, 0, stream>>>(keys, risk, idxA, list, cnt);
  k_rescan   <<<256, 256, 0, stream>>>(z, embt, enorm, znorm, list, cnt, idxA);
  k_gather   <<<NR / 16, 256, 0, stream>>>(z, emb, idxA, out, acc);
  k_loss     <<<1, 1, 0, stream>>>(acc, out);
}